// Round 10
// baseline (123.435 us; speedup 1.0000x reference)
//
#include <hip/hip_runtime.h>

// Problem constants (fixed by reference setup_inputs)
#define BATCH 8
#define NPTS  4096   // N == M == 4096
#define KD    64
#define RS    32     // rowpart slices  = m-strips  (4096/128)
#define CS    8      // colpart slices  = n-walks   (4096/512)
#define NWALK 4      // n-tiles (128 rows) walked per block = 512 n per block
#define FINF  3.0e38f

typedef float f32x4 __attribute__((ext_vector_type(4)));
typedef float f32x2 __attribute__((ext_vector_type(2)));
typedef short s16x8 __attribute__((ext_vector_type(8)));

__device__ __forceinline__ unsigned int f2bf(float f) {
  // round-to-nearest-even fp32 -> bf16 (inputs finite)
  unsigned int u = __float_as_uint(f);
  u += 0x7FFFu + ((u >> 16) & 1u);
  return u >> 16;
}

__device__ __forceinline__ float min3f(float a, float b, float c) {
  return fminf(fminf(a, b), c);   // compiler folds to v_min3_f32
}

// ---------------------------------------------------------------------------
// Prepass: convert X,Y (fp32 [32768][64]) to bf16 packed (uint [32768][32])
// and compute exact fp32 squared norms. 32 threads per row, 2 floats/thread.
// Also zeroes the reduce-phase counter (stream order makes this race-free).
__global__ __launch_bounds__(256)
void prep_kernel(const float* __restrict__ X, const float* __restrict__ Y,
                 unsigned int* __restrict__ Xbf, unsigned int* __restrict__ Ybf,
                 float* __restrict__ x2, float* __restrict__ y2,
                 unsigned int* __restrict__ counter) {
  int gid = blockIdx.x * 256 + threadIdx.x;
  if (gid == 0) *counter = 0;
  int row = gid >> 5;
  int ki  = gid & 31;
  bool isX = row < BATCH * NPTS;
  int r2 = row & (BATCH * NPTS - 1);
  const float* src = isX ? X : Y;
  f32x2 v = *(const f32x2*)(src + (size_t)r2 * KD + ki * 2);
  float s = v[0] * v[0] + v[1] * v[1];
  #pragma unroll
  for (int m = 16; m >= 1; m >>= 1) s += __shfl_xor(s, m, 64);  // stays in 32-lane half
  unsigned int packed = (f2bf(v[1]) << 16) | f2bf(v[0]);
  (isX ? Xbf : Ybf)[r2 * 32 + ki] = packed;
  if (ki == 0) (isX ? x2 : y2)[r2] = s;
}

// ---------------------------------------------------------------------------
// Main, round-10: r9 skeleton (A=Y, B=X, colmin in registers, flush once,
// zero in-loop barriers) + REGISTER PING-PONG PREFETCH: each iteration first
// issues k+1's X fragments into `nxt` registers, then MFMAs on `cur`. The
// wait before cur's use is vmcnt(12) — k+1's loads stay in flight across the
// whole compute phase (the AITER-style pipeline; possible here because the
// walk has no barrier). r9 (unroll-disable, no prefetch) was 65% stall:
// VALUBusy*dur ~= 17 us of real work inside 52 us. Grid 2048 blocks (8/CU
// queue, NWALK 8->4) for TLP. No __launch_bounds__ min-waves (spill trap).
__global__ __launch_bounds__(256)
void chamfer_main(const unsigned short* __restrict__ Xbf,
                  const unsigned short* __restrict__ Ybf,
                  const float* __restrict__ x2g, const float* __restrict__ y2g,
                  float* __restrict__ rowpart,   // [RS][B*N] min over strip's m (sq)
                  float* __restrict__ colpart) { // [CS][B*M] min over walk's n (sq)
  __shared__ float l_nm[2 * 128 * NWALK];  // 4 KB: [gm][n within walk] rowmin
  __shared__ float l_cm[2 * 128];          // 1 KB: [gn][m within strip] colmin

  const int b = blockIdx.x, ms = blockIdx.y, nw = blockIdx.z;
  const int m0 = ms * 128;           // Y strip base (128 m rows)
  const int n0 = nw * (128 * NWALK); // X walk base (512 n rows)
  const int t = threadIdx.x, w = t >> 6, lane = t & 63, c = lane & 15, q = lane >> 4;
  const int gm = w >> 1, gn = w & 1;
  const int wm = gm * 64, wn = gn * 64;

  const unsigned short* Yg = Ybf + (size_t)(b * NPTS + m0) * KD;
  const unsigned short* Xg = Xbf + (size_t)(b * NPTS + n0) * KD;

  // A-fragments (Y rows m = wm + i*16 + c), loaded ONCE. 32 VGPRs.
  s16x8 yf[4][2];
  #pragma unroll
  for (int i = 0; i < 4; ++i) {
    const unsigned short* yr = Yg + (wm + i * 16 + c) * KD + q * 8;
    yf[i][0] = *(const s16x8*)yr;
    yf[i][1] = *(const s16x8*)(yr + 32);
  }
  // y2 for this wave's m rows (m = wm + i*16 + q*4 + r). 16 VGPRs.
  const float* y2b = y2g + b * NPTS + m0;
  f32x4 y2r[4];
  #pragma unroll
  for (int i = 0; i < 4; ++i) y2r[i] = *(const f32x4*)(y2b + wm + i * 16 + q * 4);

  float macc[4][4];   // colmin accumulator: min over ALL walked n, per (i,r)
  #pragma unroll
  for (int i = 0; i < 4; ++i)
    #pragma unroll
    for (int r = 0; r < 4; ++r) macc[i][r] = FINF;

  const float* x2b = x2g + b * NPTS + n0;
  const f32x4 zacc = {0.f, 0.f, 0.f, 0.f};

  // Prime the pipeline: k=0 fragments into cur.
  s16x8 cur[4][2];
  float cx2[4];
  #pragma unroll
  for (int j = 0; j < 4; ++j) {
    const unsigned short* xr = Xg + (wn + j * 16 + c) * KD + q * 8;
    cur[j][0] = *(const s16x8*)xr;
    cur[j][1] = *(const s16x8*)(xr + 32);
    cx2[j] = x2b[wn + j * 16 + c];
  }

  #pragma clang loop unroll(disable)
  for (int k = 0; k < NWALK; ++k) {
    // PREFETCH k+1 (clamped on last iter — 12 L1-hot re-loads, harmless):
    // issued BEFORE any use of cur so cur's wait leaves these in flight.
    const int kn = (k + 1 < NWALK) ? k + 1 : k;
    s16x8 nxt[4][2];
    float nx2[4];
    #pragma unroll
    for (int j = 0; j < 4; ++j) {
      const unsigned short* xr = Xg + (kn * 128 + wn + j * 16 + c) * KD + q * 8;
      nxt[j][0] = *(const s16x8*)xr;
      nxt[j][1] = *(const s16x8*)(xr + 32);
      nx2[j] = x2b[kn * 128 + wn + j * 16 + c];
    }

    float nm[4] = {FINF, FINF, FINF, FINF};  // rowmin[n] partial, per j
    #pragma unroll
    for (int jp = 0; jp < 2; ++jp) {
      const int j0 = jp * 2, j1 = jp * 2 + 1;
      f32x4 acc0[4], acc1[4];
      #pragma unroll
      for (int i = 0; i < 4; ++i) {
        f32x4 a = __builtin_amdgcn_mfma_f32_16x16x32_bf16(yf[i][0], cur[j0][0], zacc, 0, 0, 0);
        acc0[i] = __builtin_amdgcn_mfma_f32_16x16x32_bf16(yf[i][1], cur[j0][1], a, 0, 0, 0);
        f32x4 bq = __builtin_amdgcn_mfma_f32_16x16x32_bf16(yf[i][0], cur[j1][0], zacc, 0, 0, 0);
        acc1[i] = __builtin_amdgcn_mfma_f32_16x16x32_bf16(yf[i][1], cur[j1][1], bq, 0, 0, 0);
      }
      // Epilogue (v_min3_f32): macc gets both j's in one min3; nm folds r-pairs.
      #pragma unroll
      for (int i = 0; i < 4; ++i)
        #pragma unroll
        for (int rp = 0; rp < 2; ++rp) {
          const int r0 = rp * 2, r1 = rp * 2 + 1;
          float v00 = acc0[i][r0], v01 = acc0[i][r1];
          float v10 = acc1[i][r0], v11 = acc1[i][r1];
          macc[i][r0] = min3f(macc[i][r0], fmaf(-2.f, v00, cx2[j0]), fmaf(-2.f, v10, cx2[j1]));
          macc[i][r1] = min3f(macc[i][r1], fmaf(-2.f, v01, cx2[j0]), fmaf(-2.f, v11, cx2[j1]));
          nm[j0] = min3f(nm[j0], fmaf(-2.f, v00, y2r[i][r0]), fmaf(-2.f, v01, y2r[i][r1]));
          nm[j1] = min3f(nm[j1], fmaf(-2.f, v10, y2r[i][r0]), fmaf(-2.f, v11, y2r[i][r1]));
        }
    }
    // rowmin: reduce over the 4 q-groups (m direction) — 2 shuffles per j.
    #pragma unroll
    for (int j = 0; j < 4; ++j) {
      nm[j] = fminf(nm[j], __shfl_xor(nm[j], 16, 64));
      nm[j] = fminf(nm[j], __shfl_xor(nm[j], 32, 64));
    }
    // quad q stores col group j==q: 64 consecutive floats/wave, wave-private slot.
    float sel = (q == 0) ? nm[0] : (q == 1) ? nm[1] : (q == 2) ? nm[2] : nm[3];
    l_nm[gm * (128 * NWALK) + k * 128 + wn + q * 16 + c] = sel;

    // swap: cur <- nxt (SSA copies, folded by regalloc)
    #pragma unroll
    for (int j = 0; j < 4; ++j) {
      cur[j][0] = nxt[j][0];
      cur[j][1] = nxt[j][1];
      cx2[j] = nx2[j];
    }
  }

  // colmin flush (ONCE per block): reduce macc over the 16 c-lanes...
  #pragma unroll
  for (int msk = 1; msk <= 8; msk <<= 1)
    #pragma unroll
    for (int i = 0; i < 4; ++i)
      #pragma unroll
      for (int r = 0; r < 4; ++r)
        macc[i][r] = fminf(macc[i][r], __shfl_xor(macc[i][r], msk, 64));
  // ...then c==0 lanes store all 16 (literal indices only — dynamic register
  // array indexing forces scratch lowering).
  if (c == 0) {
    #pragma unroll
    for (int i = 0; i < 4; ++i) {
      f32x4 v = {macc[i][0], macc[i][1], macc[i][2], macc[i][3]};
      *(f32x4*)&l_cm[gn * 128 + wm + i * 16 + q * 4] = v;
    }
  }
  __syncthreads();  // the ONLY barrier in the kernel

  // Final combine: rowpart (512 n, 2 per thread) and colpart (128 m).
  const size_t TOT = (size_t)BATCH * NPTS;
  float* rp_out = rowpart + (size_t)ms * TOT + b * NPTS + n0;
  #pragma unroll
  for (int u = 0; u < 2; ++u) {
    int nn = t + u * 256;
    float v = fminf(l_nm[nn], l_nm[128 * NWALK + nn]);
    rp_out[nn] = v + x2b[nn];
  }
  if (t < 128) {
    float v = fminf(l_cm[t], l_cm[128 + t]);
    colpart[(size_t)nw * TOT + b * NPTS + m0 + t] = v + y2b[t];
  }
}

// ---------------------------------------------------------------------------
// Final: min over partials, sqrt, mean — self-finalizing (no memset op). The
// last block (device-scope ticket) sums the 128 block partials -> scalar out.
__global__ __launch_bounds__(256)
void reduce_kernel(const float* __restrict__ rowpart, const float* __restrict__ colpart,
                   float* __restrict__ partials, unsigned int* __restrict__ counter,
                   float* __restrict__ out) {
  int i = blockIdx.x * 256 + threadIdx.x;
  const int TOT = BATCH * NPTS;
  float rv = FINF;
  #pragma unroll
  for (int s = 0; s < RS; ++s) rv = fminf(rv, rowpart[(size_t)s * TOT + i]);
  float s0 = sqrtf(fmaxf(rv, 0.f));
  float cv = FINF;
  #pragma unroll
  for (int s = 0; s < CS; ++s) cv = fminf(cv, colpart[(size_t)s * TOT + i]);
  s0 += sqrtf(fmaxf(cv, 0.f));
  #pragma unroll
  for (int m = 32; m >= 1; m >>= 1) s0 += __shfl_xor(s0, m, 64);
  __shared__ float wsum[4];
  if ((threadIdx.x & 63) == 0) wsum[threadIdx.x >> 6] = s0;
  __syncthreads();

  if (threadIdx.x < 64) {  // wave 0 publishes the block partial, then maybe finalizes
    unsigned int ticket = 0;
    if (threadIdx.x == 0) {
      float bsum = wsum[0] + wsum[1] + wsum[2] + wsum[3];
      atomicExch(&partials[blockIdx.x], bsum);  // device-scope visible store
      __threadfence();
      ticket = atomicAdd(counter, 1);
    }
    ticket = __shfl(ticket, 0, 64);
    if (ticket == 127) {  // all 128 partials published
      float v = atomicAdd(&partials[threadIdx.x], 0.0f) +
                atomicAdd(&partials[threadIdx.x + 64], 0.0f);
      #pragma unroll
      for (int m = 32; m >= 1; m >>= 1) v += __shfl_xor(v, m, 64);
      if (threadIdx.x == 0) out[0] = v * (1.0f / (float)TOT);
    }
  }
}

// ---------------------------------------------------------------------------
extern "C" void kernel_launch(void* const* d_in, const int* in_sizes, int n_in,
                              void* d_out, int out_size, void* d_ws, size_t ws_size,
                              hipStream_t stream) {
  const float* X = (const float*)d_in[0];  // [B, N, 64] fp32
  const float* Y = (const float*)d_in[1];  // [B, M, 64] fp32
  float* out = (float*)d_out;

  // Workspace layout (bytes):
  //   Xbf 4MB @0 | Ybf 4MB @4MB | x2 128KB @8MB | y2 128KB @8.125MB
  //   | rowpart 4MB @8.25MB | colpart 1MB @12.25MB | partials+counter @13.25MB
  char* ws = (char*)d_ws;
  unsigned int* Xbf = (unsigned int*)ws;                       // packed bf16 pairs
  unsigned int* Ybf = (unsigned int*)(ws + (4u << 20));
  float* x2 = (float*)(ws + (8u << 20));
  float* y2 = (float*)(ws + (8u << 20) + (128u << 10));
  float* rowpart = (float*)(ws + (8u << 20) + (256u << 10));
  float* colpart = (float*)(ws + (12u << 20) + (256u << 10));
  float* partials = (float*)(ws + (13u << 20) + (256u << 10));
  unsigned int* counter = (unsigned int*)(partials + 128);

  // Prepass: both inputs, 32 threads/row. Also zeroes `counter`.
  prep_kernel<<<dim3(2 * BATCH * NPTS * 32 / 256), dim3(256), 0, stream>>>(
      X, Y, Xbf, Ybf, x2, y2, counter);

  // Main: (b=8, ms=32, nw=8) = 2048 blocks; blockIdx.x=b pins batch->XCD.
  chamfer_main<<<dim3(BATCH, RS, CS), dim3(256), 0, stream>>>(
      (const unsigned short*)Xbf, (const unsigned short*)Ybf, x2, y2, rowpart, colpart);

  // Final min/sqrt/mean (self-finalizing via ticket).
  reduce_kernel<<<dim3(BATCH * NPTS / 256), dim3(256), 0, stream>>>(
      rowpart, colpart, partials, counter, out);
}